// Round 11
// baseline (201.488 us; speedup 1.0000x reference)
//
#include <hip/hip_runtime.h>
#include <hip/hip_bf16.h>

// GCNConv: out = D * (A @ (D * (X@W))) + bias,  D = rsqrt(rowsum(A)+1)
// N=100000, E=640000, C=128.
// R2..R11: 1285 -> 203us. R12: coop mega-kernel FAILED (453us), reverted.
// R13: fixed-slot CSR (one u64 atomic -> slot+deg), 3 launches, 195us.
// R14: conflict-free Wt staging (bank conflicts 4.2M->262K), 189.6us BEST.
// R15: gemm 1024 blocks REGRESSED (196us): LDS cap 4 blocks/CU -> gemm
//      filled all slots, build serialized behind it; tiles/wave 3->1.5
//      killed the prefetch pipeline. Occupancy fell 16.5->15.4%.
// R17 (this round): ATTRIBUTION SPLIT. build and gemm become separate
//      dispatches: build standalone has no LDS -> no occupancy cap, all
//      320K threads resident (640K atomics fully in flight). gemm back at
//      the proven 512-block config. Exact per-kernel counters decide the
//      next target (build>=20us -> scatter-bound; gemm~50 -> structure).

#define N_CH 128
#define WT_LD 136  // padded LDS row stride (ushorts): banks (4m+4q)%32 -> 2-way max
#define FIXS 16777216.0f  // 2^24
#define KMAX 64   // fixed slots per node row

typedef __attribute__((ext_vector_type(8))) short short8;
typedef __attribute__((ext_vector_type(4))) float f32x4;
typedef __attribute__((ext_vector_type(4))) unsigned short ushort4v;

__device__ inline unsigned short f2bf(float f) {
    unsigned u = __float_as_uint(f);
    return (unsigned short)((u + 0x7FFFu + ((u >> 16) & 1u)) >> 16);  // RNE
}
__device__ inline float bf2f(unsigned short h) {
    return __uint_as_float(((unsigned)h) << 16);
}

// ---- init: packed[i]=0; Wt[n][k]=bf16(W[k][n]) (coalesced writes) --------
__global__ __launch_bounds__(256) void init_kernel(const float* __restrict__ W,
                                                   unsigned short* __restrict__ Wt,
                                                   unsigned long long* __restrict__ packed,
                                                   int N) {
    int gid = blockIdx.x * 256 + threadIdx.x;
    for (int i = gid; i < N; i += (int)gridDim.x * 256) packed[i] = 0ULL;
    if (gid < N_CH * N_CH) {
        int n = gid >> 7, k = gid & 127;   // consecutive threads -> consecutive k
        Wt[n * N_CH + k] = f2bf(W[k * N_CH + n]);  // coalesced write; read L1-cached
    }
}

// ---- build: ONE u64 atomic/edge: hi32 ++ -> slot, lo32 += val fix8.24 ----
// No LDS -> no occupancy cap; 2 edges/thread, 1250 blocks = all resident.
__global__ __launch_bounds__(256) void build_kernel(
        const int* __restrict__ row, const int* __restrict__ col,
        const float* __restrict__ vals,
        unsigned long long* __restrict__ packed, uint2* __restrict__ epack,
        int E) {
    int e0 = blockIdx.x * 512 + threadIdx.x;
#pragma unroll
    for (int j = 0; j < 2; ++j) {
        int e = e0 + j * 256;
        if (e < E) {
            int r = row[e];
            float v = vals[e];
            unsigned fx = (unsigned)(v * FIXS);
            unsigned long long old =
                atomicAdd(&packed[r], (1ULL << 32) | (unsigned long long)fx);
            unsigned slot = (unsigned)(old >> 32);
            if (slot < KMAX)
                epack[(size_t)r * KMAX + slot] =
                    make_uint2((unsigned)col[e], __float_as_uint(v));
        }
    }
}

// ---- gemm: Ybf[n,:] = bf16(X[n,:] @ W), swapped-operand MFMA -------------
// 512 persistent blocks (2/CU), ~3 tiles/wave, next tile's X reg-prefetched.
__global__ __launch_bounds__(256) void gemm_kernel(
        const float* __restrict__ X, const unsigned short* __restrict__ Wt,
        unsigned short* __restrict__ Ybf, int N, int gemmBlocks) {
    __shared__ unsigned short Wl[N_CH * WT_LD];  // 34 KB

    const int t = threadIdx.x;
    // stage Wt (16384 ushorts = 2048 short8 chunks, 8 per thread; conflict-free)
    const short8* Wg = (const short8*)Wt;
#pragma unroll
    for (int j = 0; j < 8; ++j) {
        int idx = t + 256 * j;          // chunk id
        int r = idx >> 4, cc = idx & 15;
        *(short8*)(Wl + r * WT_LD + cc * 8) = Wg[idx];
    }
    __syncthreads();

    const int lane = t & 63;
    const int wv = t >> 6;
    const int m = lane & 15;   // X row within tile; W-fragment row select
    const int q = lane >> 4;   // k-subchunk; also output col group (q*4+reg)

    const int tiles = (N + 15) / 16;
    const int totalWaves = gemmBlocks * 4;
    int tile = blockIdx.x * 4 + wv;
    if (tile >= tiles) return;

    // prologue: first tile's X rows (raw f32)
    f32x4 pl[4], ph[4];
    {
        int rr = tile * 16 + m;
        if (rr >= N) rr = N - 1;
        const float* xr = X + (size_t)rr * N_CH + q * 8;
#pragma unroll
        for (int c = 0; c < 4; ++c) {
            pl[c] = *(const f32x4*)(xr + c * 32);
            ph[c] = *(const f32x4*)(xr + c * 32 + 4);
        }
    }

    while (true) {
        const int next = tile + totalWaves;
        const bool hasNext = next < tiles;

        // issue next tile's X loads early (hide under cvt+MFMA)
        f32x4 ql[4], qh[4];
        if (hasNext) {
            int rr2 = next * 16 + m;
            if (rr2 >= N) rr2 = N - 1;
            const float* xr2 = X + (size_t)rr2 * N_CH + q * 8;
#pragma unroll
            for (int c = 0; c < 4; ++c) {
                ql[c] = *(const f32x4*)(xr2 + c * 32);
                qh[c] = *(const f32x4*)(xr2 + c * 32 + 4);
            }
        }

        // cvt current tile f32 -> bf16 fragments
        short8 a[4];
#pragma unroll
        for (int c = 0; c < 4; ++c) {
            short8 v;
            v[0] = (short)f2bf(pl[c][0]); v[1] = (short)f2bf(pl[c][1]);
            v[2] = (short)f2bf(pl[c][2]); v[3] = (short)f2bf(pl[c][3]);
            v[4] = (short)f2bf(ph[c][0]); v[5] = (short)f2bf(ph[c][1]);
            v[6] = (short)f2bf(ph[c][2]); v[7] = (short)f2bf(ph[c][3]);
            a[c] = v;
        }

        f32x4 acc[8];
#pragma unroll
        for (int tt = 0; tt < 8; ++tt) acc[tt] = (f32x4){0.f, 0.f, 0.f, 0.f};

#pragma unroll
        for (int tt = 0; tt < 8; ++tt) {
            const unsigned short* wrow = Wl + (tt * 16 + m) * WT_LD + q * 8;
#pragma unroll
            for (int c = 0; c < 4; ++c) {
                short8 b = *(const short8*)(wrow + c * 32);
                // swapped operands: D[i=W-row][j=X-row]
                acc[tt] = __builtin_amdgcn_mfma_f32_16x16x32_bf16(b, a[c], acc[tt], 0, 0, 0);
            }
        }

        const int rr = tile * 16 + m;
        if (rr < N) {
            unsigned short* yrow = Ybf + (size_t)rr * N_CH;
#pragma unroll
            for (int tt = 0; tt < 8; ++tt) {
                unsigned lo = (unsigned)f2bf(acc[tt][0]) |
                              ((unsigned)f2bf(acc[tt][1]) << 16);
                unsigned hi = (unsigned)f2bf(acc[tt][2]) |
                              ((unsigned)f2bf(acc[tt][3]) << 16);
                *(uint2*)(yrow + tt * 16 + q * 4) = make_uint2(lo, hi);
            }
        }

        if (!hasNext) break;
#pragma unroll
        for (int c = 0; c < 4; ++c) { pl[c] = ql[c]; ph[c] = qh[c]; }
        tile = next;
    }
}

// ---- gather: out[n,:] = dinv[n] * sum_j val_j*dinv[col_j]*Y[col_j,:] + b -
// cnt and deg both come from packed[n]; dinv computed on the fly (rsqrt).
// First 4 slot loads issued CONCURRENTLY with packed[n] (no dependence).
__global__ __launch_bounds__(256) void gather_kernel(
        const unsigned long long* __restrict__ packed,
        const uint2* __restrict__ epack,
        const unsigned short* __restrict__ Ybf,
        const float* __restrict__ bias,
        float* __restrict__ out, int N) {
    unsigned gid = blockIdx.x * 256u + threadIdx.x;
    int n = gid >> 5;
    if (n >= N) return;
    int lane = gid & 31;
    int c = lane * 4;

    const uint2* base = epack + (size_t)n * KMAX;
    // issue independently: packed[n] and the first 4 slots (always-valid mem)
    uint2 f0 = base[0];
    uint2 f1 = base[1];
    uint2 f2 = base[2];
    uint2 f3 = base[3];
    unsigned long long pk = packed[n];
    int cnt = (int)(pk >> 32);
    if (cnt > KMAX) cnt = KMAX;
    float dn = rsqrtf((float)(unsigned)(pk & 0xFFFFFFFFull) * (1.0f / FIXS) + 1.0f);

    float4 acc = make_float4(0.f, 0.f, 0.f, 0.f);
    int e = 0;
    if (cnt >= 4) {
        // consume the 4 prefetched slots
        unsigned long long k0 = packed[f0.x];
        unsigned long long k1 = packed[f1.x];
        unsigned long long k2 = packed[f2.x];
        unsigned long long k3 = packed[f3.x];
        ushort4v y0 = *(const ushort4v*)(Ybf + (size_t)f0.x * N_CH + c);
        ushort4v y1 = *(const ushort4v*)(Ybf + (size_t)f1.x * N_CH + c);
        ushort4v y2 = *(const ushort4v*)(Ybf + (size_t)f2.x * N_CH + c);
        ushort4v y3 = *(const ushort4v*)(Ybf + (size_t)f3.x * N_CH + c);
        float w0 = __uint_as_float(f0.y) *
                   rsqrtf((float)(unsigned)(k0 & 0xFFFFFFFFull) * (1.0f / FIXS) + 1.0f);
        float w1 = __uint_as_float(f1.y) *
                   rsqrtf((float)(unsigned)(k1 & 0xFFFFFFFFull) * (1.0f / FIXS) + 1.0f);
        float w2 = __uint_as_float(f2.y) *
                   rsqrtf((float)(unsigned)(k2 & 0xFFFFFFFFull) * (1.0f / FIXS) + 1.0f);
        float w3 = __uint_as_float(f3.y) *
                   rsqrtf((float)(unsigned)(k3 & 0xFFFFFFFFull) * (1.0f / FIXS) + 1.0f);
        acc.x += w0 * bf2f(y0[0]) + w1 * bf2f(y1[0]) + w2 * bf2f(y2[0]) + w3 * bf2f(y3[0]);
        acc.y += w0 * bf2f(y0[1]) + w1 * bf2f(y1[1]) + w2 * bf2f(y2[1]) + w3 * bf2f(y3[1]);
        acc.z += w0 * bf2f(y0[2]) + w1 * bf2f(y1[2]) + w2 * bf2f(y2[2]) + w3 * bf2f(y3[2]);
        acc.w += w0 * bf2f(y0[3]) + w1 * bf2f(y1[3]) + w2 * bf2f(y2[3]) + w3 * bf2f(y3[3]);
        e = 4;
        for (; e + 4 <= cnt; e += 4) {
            uint2 p0 = base[e + 0];
            uint2 p1 = base[e + 1];
            uint2 p2 = base[e + 2];
            uint2 p3 = base[e + 3];
            unsigned long long j0 = packed[p0.x];
            unsigned long long j1 = packed[p1.x];
            unsigned long long j2 = packed[p2.x];
            unsigned long long j3 = packed[p3.x];
            ushort4v z0 = *(const ushort4v*)(Ybf + (size_t)p0.x * N_CH + c);
            ushort4v z1 = *(const ushort4v*)(Ybf + (size_t)p1.x * N_CH + c);
            ushort4v z2 = *(const ushort4v*)(Ybf + (size_t)p2.x * N_CH + c);
            ushort4v z3 = *(const ushort4v*)(Ybf + (size_t)p3.x * N_CH + c);
            float v0 = __uint_as_float(p0.y) *
                       rsqrtf((float)(unsigned)(j0 & 0xFFFFFFFFull) * (1.0f / FIXS) + 1.0f);
            float v1 = __uint_as_float(p1.y) *
                       rsqrtf((float)(unsigned)(j1 & 0xFFFFFFFFull) * (1.0f / FIXS) + 1.0f);
            float v2 = __uint_as_float(p2.y) *
                       rsqrtf((float)(unsigned)(j2 & 0xFFFFFFFFull) * (1.0f / FIXS) + 1.0f);
            float v3 = __uint_as_float(p3.y) *
                       rsqrtf((float)(unsigned)(j3 & 0xFFFFFFFFull) * (1.0f / FIXS) + 1.0f);
            acc.x += v0 * bf2f(z0[0]) + v1 * bf2f(z1[0]) + v2 * bf2f(z2[0]) + v3 * bf2f(z3[0]);
            acc.y += v0 * bf2f(z0[1]) + v1 * bf2f(z1[1]) + v2 * bf2f(z2[1]) + v3 * bf2f(z3[1]);
            acc.z += v0 * bf2f(z0[2]) + v1 * bf2f(z1[2]) + v2 * bf2f(z2[2]) + v3 * bf2f(z3[2]);
            acc.w += v0 * bf2f(z0[3]) + v1 * bf2f(z1[3]) + v2 * bf2f(z2[3]) + v3 * bf2f(z3[3]);
        }
    }
    for (; e < cnt; ++e) {
        uint2 p = base[e];
        unsigned long long kk = packed[p.x];
        float w = __uint_as_float(p.y) *
                  rsqrtf((float)(unsigned)(kk & 0xFFFFFFFFull) * (1.0f / FIXS) + 1.0f);
        ushort4v y = *(const ushort4v*)(Ybf + (size_t)p.x * N_CH + c);
        acc.x += w * bf2f(y[0]);
        acc.y += w * bf2f(y[1]);
        acc.z += w * bf2f(y[2]);
        acc.w += w * bf2f(y[3]);
    }

    float4 b = ((const float4*)bias)[lane];
    float4 o;
    o.x = acc.x * dn + b.x;
    o.y = acc.y * dn + b.y;
    o.z = acc.z * dn + b.z;
    o.w = acc.w * dn + b.w;
    ((float4*)(out + (size_t)n * N_CH))[lane] = o;
}

extern "C" void kernel_launch(void* const* d_in, const int* in_sizes, int n_in,
                              void* d_out, int out_size, void* d_ws, size_t ws_size,
                              hipStream_t stream) {
    const int*   row  = (const int*)d_in[0];
    const int*   col  = (const int*)d_in[1];
    const float* vals = (const float*)d_in[2];
    const float* X    = (const float*)d_in[3];
    const float* W    = (const float*)d_in[4];
    const float* bias = (const float*)d_in[5];
    float* out = (float*)d_out;

    const int E = in_sizes[0];
    const int N = in_sizes[3] / N_CH;

    // workspace: epack N*KMAX uint2 (51.2MB) | Ybf N*128 bf16 (25.6MB)
    //            | packed N u64 (0.8MB) | Wt 128*128 bf16 (32KB)
    uint2*              epack  = (uint2*)d_ws;
    unsigned short*     Ybf    = (unsigned short*)(epack + (size_t)N * KMAX);
    unsigned long long* packed = (unsigned long long*)(Ybf + (size_t)N * N_CH);
    unsigned short*     Wt     = (unsigned short*)(packed + N);

    init_kernel<<<512, 256, 0, stream>>>(W, Wt, packed, N);

    const int buildBlocks = (E + 511) / 512;          // 1250, 2 edges/thread
    build_kernel<<<buildBlocks, 256, 0, stream>>>(row, col, vals, packed, epack, E);

    const int gemmBlocks = 512;                       // persistent, 2/CU
    gemm_kernel<<<gemmBlocks, 256, 0, stream>>>(X, Wt, Ybf, N, gemmBlocks);

    unsigned gth = (unsigned)N * 32u;
    gather_kernel<<<(gth + 255) / 256, 256, 0, stream>>>(packed, epack, Ybf,
                                                         bias, out, N);
}

// Round 12
// 198.499 us; speedup vs baseline: 1.0151x; 1.0151x over previous
//
#include <hip/hip_runtime.h>
#include <hip/hip_bf16.h>

// GCNConv: out = D * (A @ (D * (X@W))) + bias,  D = rsqrt(rowsum(A)+1)
// N=100000, E=640000, C=128.
// R2..R14: 1285 -> 189.6us (CSR gather, MFMA, fixed-slot CSR via one u64
//          atomic, conflict-free LDS staging, persistent gemm).
// R15: gemm 1024 blocks regressed (LDS cap starved build concurrency).
// R17: ATTRIBUTION SPLIT. build alone = 51us at hbm 11%/VALU 0.5%: each edge
//      touches 2 random 64B lines (packed[r] RMW + epack scatter) at random-
//      access effective BW ~0.9TB/s -> pattern-roofline. gather 48.7us at
//      2.9TB/s (near pattern-roofline; 33% VALU = per-edge u64+rsqrt chain).
//      Split lost build||gemm overlap (201.5us).
// R18 (this round): (1) MERGED RECORD: node record = 64 uint2 (512B), header
//      (cnt|deg fix8.24) in slot 0, edges in slots 1..63 -> atomic and slot
//      write hit the SAME/adjacent line (~1.15 random lines/edge, was 2).
//      (2) re-fuse build+gemm (R14 config) for overlap. (3) dense dinv[]
//      (400KB, L2-resident) via tiny kernel: gather weight = val*dinv[col],
//      one 4B L2 hit instead of u64 load + rsqrt chain.

#define N_CH 128
#define WT_LD 136  // padded LDS row stride (ushorts): banks (4m+4q)%32 -> 2-way max
#define FIXS 16777216.0f  // 2^24
#define KSLOT 63   // edge slots per record (record = header + 63 slots)

typedef __attribute__((ext_vector_type(8))) short short8;
typedef __attribute__((ext_vector_type(4))) float f32x4;
typedef __attribute__((ext_vector_type(4))) unsigned short ushort4v;

__device__ inline unsigned short f2bf(float f) {
    unsigned u = __float_as_uint(f);
    return (unsigned short)((u + 0x7FFFu + ((u >> 16) & 1u)) >> 16);  // RNE
}
__device__ inline float bf2f(unsigned short h) {
    return __uint_as_float(((unsigned)h) << 16);
}

// ---- init: zero record headers; Wt[n][k]=bf16(W[k][n]) -------------------
__global__ __launch_bounds__(256) void init_kernel(const float* __restrict__ W,
                                                   unsigned short* __restrict__ Wt,
                                                   uint2* __restrict__ erec,
                                                   int N) {
    int gid = blockIdx.x * 256 + threadIdx.x;
    for (int i = gid; i < N; i += (int)gridDim.x * 256)
        *(unsigned long long*)(erec + (size_t)i * 64) = 0ULL;
    if (gid < N_CH * N_CH) {
        int n = gid >> 7, k = gid & 127;   // consecutive threads -> consecutive k
        Wt[n * N_CH + k] = f2bf(W[k * N_CH + n]);  // coalesced write; read L1-cached
    }
}

// ---- fused: gemm blocks [0,gemmBlocks) + build blocks after --------------
// build: ONE u64 atomic on record header (hi32 ++ -> slot, lo32 += val
//   fix8.24); edge written to slots 1..63 of the SAME record (same/adjacent
//   cache line as the header for low degree).
// gemm: Ybf[n,:] = bf16(X[n,:] @ W), swapped-operand MFMA, persistent waves,
//   next tile's X reg-prefetched, Wt staged conflict-free.
__global__ __launch_bounds__(256) void build_gemm_kernel(
        const int* __restrict__ row, const int* __restrict__ col,
        const float* __restrict__ vals, const float* __restrict__ X,
        const unsigned short* __restrict__ Wt,
        uint2* __restrict__ erec, unsigned short* __restrict__ Ybf,
        int N, int E, int gemmBlocks) {
    __shared__ unsigned short Wl[N_CH * WT_LD];  // 34 KB

    const int t = threadIdx.x;

    if ((int)blockIdx.x >= gemmBlocks) {
        // ---- build part: 2 edges/thread ----
        int e0 = (blockIdx.x - gemmBlocks) * 512 + t;
#pragma unroll
        for (int j = 0; j < 2; ++j) {
            int e = e0 + j * 256;
            if (e < E) {
                int r = row[e];
                float v = vals[e];
                unsigned fx = (unsigned)(v * FIXS);
                unsigned long long old = atomicAdd(
                    (unsigned long long*)(erec + (size_t)r * 64),
                    (1ULL << 32) | (unsigned long long)fx);
                unsigned slot = (unsigned)(old >> 32);
                if (slot < KSLOT)
                    erec[(size_t)r * 64 + 1 + slot] =
                        make_uint2((unsigned)col[e], __float_as_uint(v));
            }
        }
        return;
    }

    // ---- gemm part ----
    // stage Wt (16384 ushorts = 2048 short8 chunks, 8 per thread; conflict-free)
    const short8* Wg = (const short8*)Wt;
#pragma unroll
    for (int j = 0; j < 8; ++j) {
        int idx = t + 256 * j;          // chunk id
        int r = idx >> 4, cc = idx & 15;
        *(short8*)(Wl + r * WT_LD + cc * 8) = Wg[idx];
    }
    __syncthreads();

    const int lane = t & 63;
    const int wv = t >> 6;
    const int m = lane & 15;   // X row within tile; W-fragment row select
    const int q = lane >> 4;   // k-subchunk; also output col group (q*4+reg)

    const int tiles = (N + 15) / 16;
    const int totalWaves = gemmBlocks * 4;
    int tile = blockIdx.x * 4 + wv;
    if (tile >= tiles) return;

    // prologue: first tile's X rows (raw f32)
    f32x4 pl[4], ph[4];
    {
        int rr = tile * 16 + m;
        if (rr >= N) rr = N - 1;
        const float* xr = X + (size_t)rr * N_CH + q * 8;
#pragma unroll
        for (int c = 0; c < 4; ++c) {
            pl[c] = *(const f32x4*)(xr + c * 32);
            ph[c] = *(const f32x4*)(xr + c * 32 + 4);
        }
    }

    while (true) {
        const int next = tile + totalWaves;
        const bool hasNext = next < tiles;

        // issue next tile's X loads early (hide under cvt+MFMA)
        f32x4 ql[4], qh[4];
        if (hasNext) {
            int rr2 = next * 16 + m;
            if (rr2 >= N) rr2 = N - 1;
            const float* xr2 = X + (size_t)rr2 * N_CH + q * 8;
#pragma unroll
            for (int c = 0; c < 4; ++c) {
                ql[c] = *(const f32x4*)(xr2 + c * 32);
                qh[c] = *(const f32x4*)(xr2 + c * 32 + 4);
            }
        }

        // cvt current tile f32 -> bf16 fragments
        short8 a[4];
#pragma unroll
        for (int c = 0; c < 4; ++c) {
            short8 v;
            v[0] = (short)f2bf(pl[c][0]); v[1] = (short)f2bf(pl[c][1]);
            v[2] = (short)f2bf(pl[c][2]); v[3] = (short)f2bf(pl[c][3]);
            v[4] = (short)f2bf(ph[c][0]); v[5] = (short)f2bf(ph[c][1]);
            v[6] = (short)f2bf(ph[c][2]); v[7] = (short)f2bf(ph[c][3]);
            a[c] = v;
        }

        f32x4 acc[8];
#pragma unroll
        for (int tt = 0; tt < 8; ++tt) acc[tt] = (f32x4){0.f, 0.f, 0.f, 0.f};

#pragma unroll
        for (int tt = 0; tt < 8; ++tt) {
            const unsigned short* wrow = Wl + (tt * 16 + m) * WT_LD + q * 8;
#pragma unroll
            for (int c = 0; c < 4; ++c) {
                short8 b = *(const short8*)(wrow + c * 32);
                // swapped operands: D[i=W-row][j=X-row]
                acc[tt] = __builtin_amdgcn_mfma_f32_16x16x32_bf16(b, a[c], acc[tt], 0, 0, 0);
            }
        }

        const int rr = tile * 16 + m;
        if (rr < N) {
            unsigned short* yrow = Ybf + (size_t)rr * N_CH;
#pragma unroll
            for (int tt = 0; tt < 8; ++tt) {
                unsigned lo = (unsigned)f2bf(acc[tt][0]) |
                              ((unsigned)f2bf(acc[tt][1]) << 16);
                unsigned hi = (unsigned)f2bf(acc[tt][2]) |
                              ((unsigned)f2bf(acc[tt][3]) << 16);
                *(uint2*)(yrow + tt * 16 + q * 4) = make_uint2(lo, hi);
            }
        }

        if (!hasNext) break;
#pragma unroll
        for (int c = 0; c < 4; ++c) { pl[c] = ql[c]; ph[c] = qh[c]; }
        tile = next;
    }
}

// ---- dinv[n] = rsqrt(deg+1) from record headers (dense 400KB output) -----
__global__ __launch_bounds__(256) void dinv_kernel(const uint2* __restrict__ erec,
                                                   float* __restrict__ dinv, int N) {
    int n = blockIdx.x * 256 + threadIdx.x;
    if (n < N) {
        unsigned long long h = *(const unsigned long long*)(erec + (size_t)n * 64);
        dinv[n] = rsqrtf((float)(unsigned)(h & 0xFFFFFFFFull) * (1.0f / FIXS) + 1.0f);
    }
}

// ---- gather: out[n,:] = dinv[n] * sum_j val_j*dinv[col_j]*Y[col_j,:] + b -
// header + first slots share cache lines; weights via dense dinv[] (L2 hit).
__global__ __launch_bounds__(256) void gather_kernel(
        const uint2* __restrict__ erec,
        const unsigned short* __restrict__ Ybf,
        const float* __restrict__ dinv,
        const float* __restrict__ bias,
        float* __restrict__ out, int N) {
    unsigned gid = blockIdx.x * 256u + threadIdx.x;
    int n = gid >> 5;
    if (n >= N) return;
    int lane = gid & 31;
    int c = lane * 4;

    const uint2* base = erec + (size_t)n * 64;
    // header and first 4 slots: same/adjacent lines, issue concurrently
    uint2 f0 = base[1];
    uint2 f1 = base[2];
    uint2 f2 = base[3];
    uint2 f3 = base[4];
    unsigned long long pk = *(const unsigned long long*)base;
    int cnt = (int)(pk >> 32);
    if (cnt > KSLOT) cnt = KSLOT;
    float dn = dinv[n];

    float4 acc = make_float4(0.f, 0.f, 0.f, 0.f);
    int e = 0;
    if (cnt >= 4) {
        float w0 = __uint_as_float(f0.y) * dinv[f0.x];
        float w1 = __uint_as_float(f1.y) * dinv[f1.x];
        float w2 = __uint_as_float(f2.y) * dinv[f2.x];
        float w3 = __uint_as_float(f3.y) * dinv[f3.x];
        ushort4v y0 = *(const ushort4v*)(Ybf + (size_t)f0.x * N_CH + c);
        ushort4v y1 = *(const ushort4v*)(Ybf + (size_t)f1.x * N_CH + c);
        ushort4v y2 = *(const ushort4v*)(Ybf + (size_t)f2.x * N_CH + c);
        ushort4v y3 = *(const ushort4v*)(Ybf + (size_t)f3.x * N_CH + c);
        acc.x += w0 * bf2f(y0[0]) + w1 * bf2f(y1[0]) + w2 * bf2f(y2[0]) + w3 * bf2f(y3[0]);
        acc.y += w0 * bf2f(y0[1]) + w1 * bf2f(y1[1]) + w2 * bf2f(y2[1]) + w3 * bf2f(y3[1]);
        acc.z += w0 * bf2f(y0[2]) + w1 * bf2f(y1[2]) + w2 * bf2f(y2[2]) + w3 * bf2f(y3[2]);
        acc.w += w0 * bf2f(y0[3]) + w1 * bf2f(y1[3]) + w2 * bf2f(y2[3]) + w3 * bf2f(y3[3]);
        e = 4;
        for (; e + 4 <= cnt; e += 4) {
            uint2 p0 = base[1 + e + 0];
            uint2 p1 = base[1 + e + 1];
            uint2 p2 = base[1 + e + 2];
            uint2 p3 = base[1 + e + 3];
            float v0 = __uint_as_float(p0.y) * dinv[p0.x];
            float v1 = __uint_as_float(p1.y) * dinv[p1.x];
            float v2 = __uint_as_float(p2.y) * dinv[p2.x];
            float v3 = __uint_as_float(p3.y) * dinv[p3.x];
            ushort4v z0 = *(const ushort4v*)(Ybf + (size_t)p0.x * N_CH + c);
            ushort4v z1 = *(const ushort4v*)(Ybf + (size_t)p1.x * N_CH + c);
            ushort4v z2 = *(const ushort4v*)(Ybf + (size_t)p2.x * N_CH + c);
            ushort4v z3 = *(const ushort4v*)(Ybf + (size_t)p3.x * N_CH + c);
            acc.x += v0 * bf2f(z0[0]) + v1 * bf2f(z1[0]) + v2 * bf2f(z2[0]) + v3 * bf2f(z3[0]);
            acc.y += v0 * bf2f(z0[1]) + v1 * bf2f(z1[1]) + v2 * bf2f(z2[1]) + v3 * bf2f(z3[1]);
            acc.z += v0 * bf2f(z0[2]) + v1 * bf2f(z1[2]) + v2 * bf2f(z2[2]) + v3 * bf2f(z3[2]);
            acc.w += v0 * bf2f(z0[3]) + v1 * bf2f(z1[3]) + v2 * bf2f(z2[3]) + v3 * bf2f(z3[3]);
        }
    }
    for (; e < cnt; ++e) {
        uint2 p = base[1 + e];
        float w = __uint_as_float(p.y) * dinv[p.x];
        ushort4v y = *(const ushort4v*)(Ybf + (size_t)p.x * N_CH + c);
        acc.x += w * bf2f(y[0]);
        acc.y += w * bf2f(y[1]);
        acc.z += w * bf2f(y[2]);
        acc.w += w * bf2f(y[3]);
    }

    float4 b = ((const float4*)bias)[lane];
    float4 o;
    o.x = acc.x * dn + b.x;
    o.y = acc.y * dn + b.y;
    o.z = acc.z * dn + b.z;
    o.w = acc.w * dn + b.w;
    ((float4*)(out + (size_t)n * N_CH))[lane] = o;
}

extern "C" void kernel_launch(void* const* d_in, const int* in_sizes, int n_in,
                              void* d_out, int out_size, void* d_ws, size_t ws_size,
                              hipStream_t stream) {
    const int*   row  = (const int*)d_in[0];
    const int*   col  = (const int*)d_in[1];
    const float* vals = (const float*)d_in[2];
    const float* X    = (const float*)d_in[3];
    const float* W    = (const float*)d_in[4];
    const float* bias = (const float*)d_in[5];
    float* out = (float*)d_out;

    const int E = in_sizes[0];
    const int N = in_sizes[3] / N_CH;

    // workspace: erec N*64 uint2 (51.2MB, header+63 slots per node)
    //            | Ybf N*128 bf16 (25.6MB) | dinv N f32 | Wt 128*128 bf16
    uint2*          erec = (uint2*)d_ws;
    unsigned short* Ybf  = (unsigned short*)(erec + (size_t)N * 64);
    float*          dinv = (float*)(Ybf + (size_t)N * N_CH);
    unsigned short* Wt   = (unsigned short*)(dinv + N);

    init_kernel<<<512, 256, 0, stream>>>(W, Wt, erec, N);

    const int gemmBlocks = 512;                       // persistent, 2/CU
    const int buildBlocks = (E + 511) / 512;          // 1250, 2 edges/thread
    build_gemm_kernel<<<gemmBlocks + buildBlocks, 256, 0, stream>>>(
        row, col, vals, X, Wt, erec, Ybf, N, E, gemmBlocks);

    dinv_kernel<<<(N + 255) / 256, 256, 0, stream>>>(erec, dinv, N);

    unsigned gth = (unsigned)N * 32u;
    gather_kernel<<<(gth + 255) / 256, 256, 0, stream>>>(erec, Ybf, dinv,
                                                         bias, out, N);
}

// Round 13
// 192.582 us; speedup vs baseline: 1.0462x; 1.0307x over previous
//
#include <hip/hip_runtime.h>
#include <hip/hip_bf16.h>

// GCNConv: out = D * (A @ (D * (X@W))) + bias,  D = rsqrt(rowsum(A)+1)
// N=100000, E=640000, C=128.
// R2..R14: 1285 -> 189.6us BEST (CSR gather, MFMA, fixed-slot CSR via one
//          u64 atomic on COMPACT packed[], conflict-free LDS staging,
//          persistent gemm, fused build||gemm).
// R17 split: build alone 51us (atomic-throughput floor ~15-20Gop/s on the
//          fabric + 64B-line scatter), gather 48.7us (33% VALU = u64+rsqrt
//          chain), gemm ~38us.
// R18: merged-record REGRESSED (198.5): moved atomics from L2-hot 0.8MB
//          packed onto cold random 512B records. Reverted.
// R19 (this round): best-of-measured composite. R14 structure exactly
//          (compact packed atomics + separate epack + fused 512 gemm/1250
//          build blocks) + gather-side wins from R18: dense dinv[] (400KB,
//          L2-resident) via tiny kernel; gather weight = val*dinv[col] (one
//          4B L2 hit, no u64/rsqrt chain); first-4 slot prefetch.
//          Floor model: ~104us kernels + ~85us harness window ~= 188us wall.

#define N_CH 128
#define WT_LD 136  // padded LDS row stride (ushorts): banks (4m+4q)%32 -> 2-way max
#define FIXS 16777216.0f  // 2^24
#define KMAX 64   // fixed slots per node row

typedef __attribute__((ext_vector_type(8))) short short8;
typedef __attribute__((ext_vector_type(4))) float f32x4;
typedef __attribute__((ext_vector_type(4))) unsigned short ushort4v;

__device__ inline unsigned short f2bf(float f) {
    unsigned u = __float_as_uint(f);
    return (unsigned short)((u + 0x7FFFu + ((u >> 16) & 1u)) >> 16);  // RNE
}
__device__ inline float bf2f(unsigned short h) {
    return __uint_as_float(((unsigned)h) << 16);
}

// ---- init: packed[i]=0; Wt[n][k]=bf16(W[k][n]) (coalesced writes) --------
__global__ __launch_bounds__(256) void init_kernel(const float* __restrict__ W,
                                                   unsigned short* __restrict__ Wt,
                                                   unsigned long long* __restrict__ packed,
                                                   int N) {
    int gid = blockIdx.x * 256 + threadIdx.x;
    for (int i = gid; i < N; i += (int)gridDim.x * 256) packed[i] = 0ULL;
    if (gid < N_CH * N_CH) {
        int n = gid >> 7, k = gid & 127;   // consecutive threads -> consecutive k
        Wt[n * N_CH + k] = f2bf(W[k * N_CH + n]);  // coalesced write; read L1-cached
    }
}

// ---- fused: gemm blocks [0,gemmBlocks) + build blocks after --------------
// build: ONE u64 atomic/edge on COMPACT packed[] (hi32 ++ -> slot, lo32 +=
//   val fix8.24); epack[row*KMAX+slot] = {col,val} (unavoidable line scatter).
// gemm: Ybf[n,:] = bf16(X[n,:] @ W), swapped-operand MFMA, persistent waves,
//   next tile's X reg-prefetched, Wt staged conflict-free.
__global__ __launch_bounds__(256) void build_gemm_kernel(
        const int* __restrict__ row, const int* __restrict__ col,
        const float* __restrict__ vals, const float* __restrict__ X,
        const unsigned short* __restrict__ Wt,
        unsigned long long* __restrict__ packed, uint2* __restrict__ epack,
        unsigned short* __restrict__ Ybf, int N, int E, int gemmBlocks) {
    __shared__ unsigned short Wl[N_CH * WT_LD];  // 34 KB

    const int t = threadIdx.x;

    if ((int)blockIdx.x >= gemmBlocks) {
        // ---- build part: 2 edges/thread ----
        int e0 = (blockIdx.x - gemmBlocks) * 512 + t;
#pragma unroll
        for (int j = 0; j < 2; ++j) {
            int e = e0 + j * 256;
            if (e < E) {
                int r = row[e];
                float v = vals[e];
                unsigned fx = (unsigned)(v * FIXS);
                unsigned long long old =
                    atomicAdd(&packed[r], (1ULL << 32) | (unsigned long long)fx);
                unsigned slot = (unsigned)(old >> 32);
                if (slot < KMAX)
                    epack[(size_t)r * KMAX + slot] =
                        make_uint2((unsigned)col[e], __float_as_uint(v));
            }
        }
        return;
    }

    // ---- gemm part ----
    // stage Wt (16384 ushorts = 2048 short8 chunks, 8 per thread; conflict-free)
    const short8* Wg = (const short8*)Wt;
#pragma unroll
    for (int j = 0; j < 8; ++j) {
        int idx = t + 256 * j;          // chunk id
        int r = idx >> 4, cc = idx & 15;
        *(short8*)(Wl + r * WT_LD + cc * 8) = Wg[idx];
    }
    __syncthreads();

    const int lane = t & 63;
    const int wv = t >> 6;
    const int m = lane & 15;   // X row within tile; W-fragment row select
    const int q = lane >> 4;   // k-subchunk; also output col group (q*4+reg)

    const int tiles = (N + 15) / 16;
    const int totalWaves = gemmBlocks * 4;
    int tile = blockIdx.x * 4 + wv;
    if (tile >= tiles) return;

    // prologue: first tile's X rows (raw f32)
    f32x4 pl[4], ph[4];
    {
        int rr = tile * 16 + m;
        if (rr >= N) rr = N - 1;
        const float* xr = X + (size_t)rr * N_CH + q * 8;
#pragma unroll
        for (int c = 0; c < 4; ++c) {
            pl[c] = *(const f32x4*)(xr + c * 32);
            ph[c] = *(const f32x4*)(xr + c * 32 + 4);
        }
    }

    while (true) {
        const int next = tile + totalWaves;
        const bool hasNext = next < tiles;

        // issue next tile's X loads early (hide under cvt+MFMA)
        f32x4 ql[4], qh[4];
        if (hasNext) {
            int rr2 = next * 16 + m;
            if (rr2 >= N) rr2 = N - 1;
            const float* xr2 = X + (size_t)rr2 * N_CH + q * 8;
#pragma unroll
            for (int c = 0; c < 4; ++c) {
                ql[c] = *(const f32x4*)(xr2 + c * 32);
                qh[c] = *(const f32x4*)(xr2 + c * 32 + 4);
            }
        }

        // cvt current tile f32 -> bf16 fragments
        short8 a[4];
#pragma unroll
        for (int c = 0; c < 4; ++c) {
            short8 v;
            v[0] = (short)f2bf(pl[c][0]); v[1] = (short)f2bf(pl[c][1]);
            v[2] = (short)f2bf(pl[c][2]); v[3] = (short)f2bf(pl[c][3]);
            v[4] = (short)f2bf(ph[c][0]); v[5] = (short)f2bf(ph[c][1]);
            v[6] = (short)f2bf(ph[c][2]); v[7] = (short)f2bf(ph[c][3]);
            a[c] = v;
        }

        f32x4 acc[8];
#pragma unroll
        for (int tt = 0; tt < 8; ++tt) acc[tt] = (f32x4){0.f, 0.f, 0.f, 0.f};

#pragma unroll
        for (int tt = 0; tt < 8; ++tt) {
            const unsigned short* wrow = Wl + (tt * 16 + m) * WT_LD + q * 8;
#pragma unroll
            for (int c = 0; c < 4; ++c) {
                short8 b = *(const short8*)(wrow + c * 32);
                // swapped operands: D[i=W-row][j=X-row]
                acc[tt] = __builtin_amdgcn_mfma_f32_16x16x32_bf16(b, a[c], acc[tt], 0, 0, 0);
            }
        }

        const int rr = tile * 16 + m;
        if (rr < N) {
            unsigned short* yrow = Ybf + (size_t)rr * N_CH;
#pragma unroll
            for (int tt = 0; tt < 8; ++tt) {
                unsigned lo = (unsigned)f2bf(acc[tt][0]) |
                              ((unsigned)f2bf(acc[tt][1]) << 16);
                unsigned hi = (unsigned)f2bf(acc[tt][2]) |
                              ((unsigned)f2bf(acc[tt][3]) << 16);
                *(uint2*)(yrow + tt * 16 + q * 4) = make_uint2(lo, hi);
            }
        }

        if (!hasNext) break;
#pragma unroll
        for (int c = 0; c < 4; ++c) { pl[c] = ql[c]; ph[c] = qh[c]; }
        tile = next;
    }
}

// ---- dinv[n] = rsqrt(deg+1) from packed (dense 400KB, L2-resident) -------
__global__ __launch_bounds__(256) void dinv_kernel(const unsigned long long* __restrict__ packed,
                                                   float* __restrict__ dinv, int N) {
    int n = blockIdx.x * 256 + threadIdx.x;
    if (n < N) {
        dinv[n] = rsqrtf((float)(unsigned)(packed[n] & 0xFFFFFFFFull) * (1.0f / FIXS) + 1.0f);
    }
}

// ---- gather: out[n,:] = dinv[n] * sum_j val_j*dinv[col_j]*Y[col_j,:] + b -
// weights via dense dinv[] (4B L2 hit); first-4 slot prefetch overlaps the
// packed[n] header load.
__global__ __launch_bounds__(256) void gather_kernel(
        const unsigned long long* __restrict__ packed,
        const uint2* __restrict__ epack,
        const unsigned short* __restrict__ Ybf,
        const float* __restrict__ dinv,
        const float* __restrict__ bias,
        float* __restrict__ out, int N) {
    unsigned gid = blockIdx.x * 256u + threadIdx.x;
    int n = gid >> 5;
    if (n >= N) return;
    int lane = gid & 31;
    int c = lane * 4;

    const uint2* base = epack + (size_t)n * KMAX;
    // issue independently: packed[n] and the first 4 slots (always-valid mem)
    uint2 f0 = base[0];
    uint2 f1 = base[1];
    uint2 f2 = base[2];
    uint2 f3 = base[3];
    unsigned long long pk = packed[n];
    int cnt = (int)(pk >> 32);
    if (cnt > KMAX) cnt = KMAX;
    float dn = dinv[n];

    float4 acc = make_float4(0.f, 0.f, 0.f, 0.f);
    int e = 0;
    if (cnt >= 4) {
        float w0 = __uint_as_float(f0.y) * dinv[f0.x];
        float w1 = __uint_as_float(f1.y) * dinv[f1.x];
        float w2 = __uint_as_float(f2.y) * dinv[f2.x];
        float w3 = __uint_as_float(f3.y) * dinv[f3.x];
        ushort4v y0 = *(const ushort4v*)(Ybf + (size_t)f0.x * N_CH + c);
        ushort4v y1 = *(const ushort4v*)(Ybf + (size_t)f1.x * N_CH + c);
        ushort4v y2 = *(const ushort4v*)(Ybf + (size_t)f2.x * N_CH + c);
        ushort4v y3 = *(const ushort4v*)(Ybf + (size_t)f3.x * N_CH + c);
        acc.x += w0 * bf2f(y0[0]) + w1 * bf2f(y1[0]) + w2 * bf2f(y2[0]) + w3 * bf2f(y3[0]);
        acc.y += w0 * bf2f(y0[1]) + w1 * bf2f(y1[1]) + w2 * bf2f(y2[1]) + w3 * bf2f(y3[1]);
        acc.z += w0 * bf2f(y0[2]) + w1 * bf2f(y1[2]) + w2 * bf2f(y2[2]) + w3 * bf2f(y3[2]);
        acc.w += w0 * bf2f(y0[3]) + w1 * bf2f(y1[3]) + w2 * bf2f(y2[3]) + w3 * bf2f(y3[3]);
        e = 4;
        for (; e + 4 <= cnt; e += 4) {
            uint2 p0 = base[e + 0];
            uint2 p1 = base[e + 1];
            uint2 p2 = base[e + 2];
            uint2 p3 = base[e + 3];
            float v0 = __uint_as_float(p0.y) * dinv[p0.x];
            float v1 = __uint_as_float(p1.y) * dinv[p1.x];
            float v2 = __uint_as_float(p2.y) * dinv[p2.x];
            float v3 = __uint_as_float(p3.y) * dinv[p3.x];
            ushort4v z0 = *(const ushort4v*)(Ybf + (size_t)p0.x * N_CH + c);
            ushort4v z1 = *(const ushort4v*)(Ybf + (size_t)p1.x * N_CH + c);
            ushort4v z2 = *(const ushort4v*)(Ybf + (size_t)p2.x * N_CH + c);
            ushort4v z3 = *(const ushort4v*)(Ybf + (size_t)p3.x * N_CH + c);
            acc.x += v0 * bf2f(z0[0]) + v1 * bf2f(z1[0]) + v2 * bf2f(z2[0]) + v3 * bf2f(z3[0]);
            acc.y += v0 * bf2f(z0[1]) + v1 * bf2f(z1[1]) + v2 * bf2f(z2[1]) + v3 * bf2f(z3[1]);
            acc.z += v0 * bf2f(z0[2]) + v1 * bf2f(z1[2]) + v2 * bf2f(z2[2]) + v3 * bf2f(z3[2]);
            acc.w += v0 * bf2f(z0[3]) + v1 * bf2f(z1[3]) + v2 * bf2f(z2[3]) + v3 * bf2f(z3[3]);
        }
    }
    for (; e < cnt; ++e) {
        uint2 p = base[e];
        float w = __uint_as_float(p.y) * dinv[p.x];
        ushort4v y = *(const ushort4v*)(Ybf + (size_t)p.x * N_CH + c);
        acc.x += w * bf2f(y[0]);
        acc.y += w * bf2f(y[1]);
        acc.z += w * bf2f(y[2]);
        acc.w += w * bf2f(y[3]);
    }

    float4 b = ((const float4*)bias)[lane];
    float4 o;
    o.x = acc.x * dn + b.x;
    o.y = acc.y * dn + b.y;
    o.z = acc.z * dn + b.z;
    o.w = acc.w * dn + b.w;
    ((float4*)(out + (size_t)n * N_CH))[lane] = o;
}

extern "C" void kernel_launch(void* const* d_in, const int* in_sizes, int n_in,
                              void* d_out, int out_size, void* d_ws, size_t ws_size,
                              hipStream_t stream) {
    const int*   row  = (const int*)d_in[0];
    const int*   col  = (const int*)d_in[1];
    const float* vals = (const float*)d_in[2];
    const float* X    = (const float*)d_in[3];
    const float* W    = (const float*)d_in[4];
    const float* bias = (const float*)d_in[5];
    float* out = (float*)d_out;

    const int E = in_sizes[0];
    const int N = in_sizes[3] / N_CH;

    // workspace: epack N*KMAX uint2 (51.2MB) | Ybf N*128 bf16 (25.6MB)
    //            | packed N u64 (0.8MB) | dinv N f32 (0.4MB) | Wt 32KB
    uint2*              epack  = (uint2*)d_ws;
    unsigned short*     Ybf    = (unsigned short*)(epack + (size_t)N * KMAX);
    unsigned long long* packed = (unsigned long long*)(Ybf + (size_t)N * N_CH);
    float*              dinv   = (float*)(packed + N);
    unsigned short*     Wt     = (unsigned short*)(dinv + N);

    init_kernel<<<512, 256, 0, stream>>>(W, Wt, packed, N);

    const int gemmBlocks = 512;                       // persistent, 2/CU
    const int buildBlocks = (E + 511) / 512;          // 1250, 2 edges/thread
    build_gemm_kernel<<<gemmBlocks + buildBlocks, 256, 0, stream>>>(
        row, col, vals, X, Wt, packed, epack, Ybf, N, E, gemmBlocks);

    dinv_kernel<<<(N + 255) / 256, 256, 0, stream>>>(packed, dinv, N);

    unsigned gth = (unsigned)N * 32u;
    gather_kernel<<<(gth + 255) / 256, 256, 0, stream>>>(packed, epack, Ybf,
                                                         dinv, bias, out, N);
}